// Round 3
// baseline (148.968 us; speedup 1.0000x reference)
//
#include <hip/hip_runtime.h>
#include <hip/hip_bf16.h>

// ---------------------------------------------------------------------------
// HiddenEdgeDistanceMLP on MI355X (gfx950)
//
// reference:  s = s_lig[l] + s_poc[p]          [E,256]
//             h1 = silu(s @ W1.T + b1)         [E,128]
//             h2 = silu(h1 @ W2.T + b2)        [E,64]
//             out = relu(h2 @ W3.T + b3)       [E]
//
// v15 (R2): ZERO-LDS edge kernel. R1 post-mortem: two different schedules
//   (2560 blocks vs 1024 persistent) both land at ~51us, VALUBusy 65-70%,
//   busy ~34us, occupancy ~2 blocks/CU -> not packing-bound; ~35% idle is
//   per-wave latency (ds_read lgkm waits + dep chains) that ~2 waves/SIMD
//   can't cover. Fix: remove ALL LDS from the inner loop:
//    * W2 B-frags in REGISTERS (16 x bf16x8 = 64 VGPR), per-lane direct
//      global load once per block (W2=32KB, L2-resident). Same f2bf RNE
//      values as the old LDS staging -> bitwise identical.
//    * Pocket rows in REGISTERS (32 VGPR: lane c holds row c slices),
//      persistent across consecutive items sharing (b,jt) (<=2 reloads
//      per 10-item run).
//    * Ligand row in registers, prefetched into dead buffer post-ks-loop.
//    * Wave item = 1 atom x 16 pockets; 40960 items = 4096 waves x 10
//      (uniform persistent, 1024 blocks x 4 independent waves, no barriers).
//   Inner loop = pure reg VALU + 4 MFMA per ks. Math bitwise identical to
//   v14 (same silu/RHU-pack/MFMA chain order) -> absmax 0.001953125.
// v12/v14 mechanisms kept: b2 folded into acc init, single rhu-bf16 h1,
//   DPP rowsum, perm packing, no min-waves bound (VGPR cliff -> spills).
// ---------------------------------------------------------------------------

#define B_CPLX   128
#define NLB      32
#define NPB      160
#define SDIM     256
#define H1DIM    128
#define NL_TOT   (B_CPLX * NLB)         // 4096
#define NP_TOT   (B_CPLX * NPB)         // 20480
#define NROWS    (NL_TOT + NP_TOT)      // 24576
#define E_TOT    (B_CPLX * NLB * NPB)   // 655360

#define W1_LDS_STRIDE 264               // 256 + 8 bf16 pad
#define JT_CHUNK 16                     // pocket rows per item

#define ITEMS_PER_WAVE 10
#define NITEMS        (B_CPLX * 10 * NLB)        // 40960 = b x jt x atom
#define EDGE_BLOCKS   (NITEMS / ITEMS_PER_WAVE / 4)  // 1024 blocks x 4 waves

typedef __bf16 bf16x8 __attribute__((ext_vector_type(8)));
typedef unsigned short ushortx8 __attribute__((ext_vector_type(8)));
typedef unsigned short ushortx4 __attribute__((ext_vector_type(4)));
typedef unsigned uintx4 __attribute__((ext_vector_type(4)));
typedef float f32x4 __attribute__((ext_vector_type(4)));

__device__ __forceinline__ unsigned short f2bf(float f) {
    unsigned u = __builtin_bit_cast(unsigned, f);
    u += 0x7FFFu + ((u >> 16) & 1u);          // round-to-nearest-even
    return (unsigned short)(u >> 16);
}

// v_perm_b32: pack hi16(x0) low, hi16(x1) high (1 op)
__device__ __forceinline__ unsigned perm_hi16u(unsigned u0, unsigned u1) {
    return __builtin_amdgcn_perm(u1, u0, 0x07060302u);
}

// round-half-up bf16 pair pack: bitpattern + 0x8000 then take hi16.
__device__ __forceinline__ unsigned pack2_rhu(float x0, float x1) {
    unsigned u0 = __builtin_bit_cast(unsigned, x0) + 0x8000u;
    unsigned u1 = __builtin_bit_cast(unsigned, x1) + 0x8000u;
    return perm_hi16u(u0, u1);
}

__device__ __forceinline__ bf16x8 pack8_rhu(const float* x) {
    uintx4 h;
#pragma unroll
    for (int j = 0; j < 4; ++j) h[j] = pack2_rhu(x[2 * j], x[2 * j + 1]);
    return __builtin_bit_cast(bf16x8, h);
}

// hi/lo exact split (proj only): hi = trunc bf16, lo = bf16(x - hi)
__device__ __forceinline__ void pack_split(const float* x, bf16x8& hi, bf16x8& lo) {
    uintx4 h, l;
#pragma unroll
    for (int j = 0; j < 4; ++j) {
        float x0 = x[2 * j], x1 = x[2 * j + 1];
        unsigned u0 = __builtin_bit_cast(unsigned, x0);
        unsigned u1 = __builtin_bit_cast(unsigned, x1);
        h[j] = perm_hi16u(u0, u1);
        float hf0 = __builtin_bit_cast(float, u0 & 0xFFFF0000u);
        float hf1 = __builtin_bit_cast(float, u1 & 0xFFFF0000u);
        l[j] = pack2_rhu(x0 - hf0, x1 - hf1);
    }
    hi = __builtin_bit_cast(bf16x8, h);
    lo = __builtin_bit_cast(bf16x8, l);
}

__device__ __forceinline__ float fast_silu(float x) {
    return x * __builtin_amdgcn_rcpf(1.0f + __expf(-x));
}

// full-rate 16-lane row reduction: v_add_f32 + dpp row_ror 1,2,4,8
__device__ __forceinline__ float rowsum16(float s) {
    int b;
    b = __builtin_bit_cast(int, s);
    b = __builtin_amdgcn_update_dpp(b, b, 0x121, 0xF, 0xF, false);  // ror:1
    s += __builtin_bit_cast(float, b);
    b = __builtin_bit_cast(int, s);
    b = __builtin_amdgcn_update_dpp(b, b, 0x122, 0xF, 0xF, false);  // ror:2
    s += __builtin_bit_cast(float, b);
    b = __builtin_bit_cast(int, s);
    b = __builtin_amdgcn_update_dpp(b, b, 0x124, 0xF, 0xF, false);  // ror:4
    s += __builtin_bit_cast(float, b);
    b = __builtin_bit_cast(int, s);
    b = __builtin_amdgcn_update_dpp(b, b, 0x128, 0xF, 0xF, false);  // ror:8
    s += __builtin_bit_cast(float, b);
    return s;
}

// ---------------------------------------------------------------------------
// Kernel 1: Z[m][n] = X[m] @ W1[n] (+ b1[n] if m is a ligand row)
//   768 blocks = 384 row-tile groups x 2 N-halves; hi/lo split -> Z ~exact.
//   (verbatim v12)
// ---------------------------------------------------------------------------
__global__ __launch_bounds__(256) void proj_kernel(
    const float* __restrict__ s_lig, const float* __restrict__ s_poc,
    const float* __restrict__ W1,    const float* __restrict__ b1,
    float* __restrict__ Z)
{
    __shared__ unsigned short w1s[64 * W1_LDS_STRIDE];   // 33.8 KB

    const int tid  = threadIdx.x;
    const int tg   = blockIdx.x >> 1;             // row-tile group 0..383
    const int half = blockIdx.x & 1;              // N half

    {
        const f32x4* w4 = (const f32x4*)(W1 + (size_t)half * 64 * SDIM);  // 4096 units
#pragma unroll
        for (int r = 0; r < 2; ++r) {
            f32x4 t[8];
#pragma unroll
            for (int s = 0; s < 8; ++s) t[s] = w4[tid + (r * 8 + s) * 256];
#pragma unroll
            for (int s = 0; s < 8; ++s) {
                const int u = tid + (r * 8 + s) * 256;
                const int n = u >> 6;             // 64 f32x4 per 256-col row
                const int k4 = u & 63;
                ushortx4 us;
#pragma unroll
                for (int j = 0; j < 4; ++j) us[j] = f2bf(t[s][j]);
                *(ushortx4*)(&w1s[n * W1_LDS_STRIDE + k4 * 4]) = us;
            }
        }
    }
    __syncthreads();

    const int lane = tid & 63;
    const int widx = tid >> 6;
    const int c    = lane & 15;
    const int q    = lane >> 4;
    const int tile = tg * 4 + widx;               // 0..1535
    const int row  = tile * 16 + c;

    const float* src = (row < NL_TOT) ? (s_lig + (size_t)row * SDIM)
                                      : (s_poc + (size_t)(row - NL_TOT) * SDIM);

    f32x4 acc[4];
#pragma unroll
    for (int nt = 0; nt < 4; ++nt) acc[nt] = (f32x4){0.f, 0.f, 0.f, 0.f};

#pragma unroll
    for (int ks = 0; ks < 8; ++ks) {              // K = 256 = 8 x 32
        const int k0 = ks * 32 + q * 8;
        f32x4 xa = *reinterpret_cast<const f32x4*>(src + k0);
        f32x4 xb = *reinterpret_cast<const f32x4*>(src + k0 + 4);
        float xv[8] = {xa[0], xa[1], xa[2], xa[3], xb[0], xb[1], xb[2], xb[3]};
        bf16x8 ahi, alo;
        pack_split(xv, ahi, alo);
        bf16x8 bfrag[4];
#pragma unroll
        for (int nt = 0; nt < 4; ++nt)
            bfrag[nt] = *reinterpret_cast<const bf16x8*>(
                &w1s[(nt * 16 + c) * W1_LDS_STRIDE + k0]);
#pragma unroll
        for (int nt = 0; nt < 4; ++nt)            // hi pass (dep distance 4)
            acc[nt] = __builtin_amdgcn_mfma_f32_16x16x32_bf16(ahi, bfrag[nt], acc[nt], 0, 0, 0);
#pragma unroll
        for (int nt = 0; nt < 4; ++nt)            // lo pass
            acc[nt] = __builtin_amdgcn_mfma_f32_16x16x32_bf16(alo, bfrag[nt], acc[nt], 0, 0, 0);
    }

    // C/D layout: col n' = lane&15, row m = q*4 + reg
    const int mb = tile * 16 + q * 4;
#pragma unroll
    for (int nt = 0; nt < 4; ++nt) {
        const int n = half * 64 + nt * 16 + c;
        const float bias = b1[n];
#pragma unroll
        for (int r = 0; r < 4; ++r) {
            const int m = mb + r;
            float v = acc[nt][r];
            if (m < NL_TOT) v += bias;            // fold b1 into ligand rows only
            Z[(size_t)m * H1DIM + n] = v;
        }
    }
}

// ---------------------------------------------------------------------------
// Kernel 2 (zero-LDS persistent): 1024 blocks x 4 independent waves.
//   Wave item = (b, jt, atom): 1 atom x 16 pockets. 4096 waves x 10 items.
//   id = (b*10 + jt)*32 + atom  -> consecutive ids share (b,jt) for 32
//   items, so a 10-item run reloads pocket regs at most once mid-run.
// ---------------------------------------------------------------------------
__global__ __launch_bounds__(256) void edge_kernel(
    const float* __restrict__ Z,
    const float* __restrict__ W2, const float* __restrict__ b2,
    const float* __restrict__ W3, const float* __restrict__ b3,
    float* __restrict__ out)
{
    const int tid  = threadIdx.x;
    const int lane = tid & 63;
    const int widx = tid >> 6;
    const int c    = lane & 15;
    const int q    = lane >> 4;

    // ---- W2 B-fragments in registers (64 VGPR), per-lane direct load ----
    //   frag f = nt*4 + ks: lane holds W2[n = nt*16 + c][ks*32 + q*8 .. +8]
    //   (same f2bf RNE values as the old LDS staging -> bitwise identical)
    bf16x8 wfr[16];
#pragma unroll
    for (int f = 0; f < 16; ++f) {
        const int nt = f >> 2;
        const int ks = f & 3;
        const float* wsrc = W2 + (size_t)(nt * 16 + c) * H1DIM + ks * 32 + q * 8;
        f32x4 wa = *(const f32x4*)wsrc;
        f32x4 wb = *(const f32x4*)(wsrc + 4);
        ushortx8 us;
#pragma unroll
        for (int j = 0; j < 4; ++j) {
            us[j]     = f2bf(wa[j]);
            us[4 + j] = f2bf(wb[j]);
        }
        wfr[f] = __builtin_bit_cast(bf16x8, us);
    }

    float b2f[4], w3f[4];
#pragma unroll
    for (int nt = 0; nt < 4; ++nt) {
        b2f[nt] = b2[nt * 16 + c];
        w3f[nt] = W3[nt * 16 + c];
    }
    const float b3v = b3[0];

    // ---- item schedule: 10 consecutive ids per wave ----
    int id = (blockIdx.x * 4 + widx) * ITEMS_PER_WAVE;
    int b  = id / 320;
    int rr = id - b * 320;
    int jt = rr >> 5;                             // 0..9
    int at = rr & 31;                             // atom 0..31

    // pocket regs: lane holds Z row (NL_TOT + b*160 + jt*16 + c), all 4 K-slices
    f32x4 pk[4][2];
    {
        const float* pkg = Z + (size_t)(NL_TOT + b * NPB + jt * JT_CHUNK + c) * H1DIM;
#pragma unroll
        for (int ks = 0; ks < 4; ++ks) {
            const int k0 = ks * 32 + q * 8;
            pk[ks][0] = *(const f32x4*)(pkg + k0);
            pk[ks][1] = *(const f32x4*)(pkg + k0 + 4);
        }
    }

    // ligand regs: atom row (wave-uniform across c; per-lane slice by q)
    f32x4 lr[4][2];
    {
        const float* lrg = Z + (size_t)(b * NLB + at) * H1DIM;
#pragma unroll
        for (int ks = 0; ks < 4; ++ks) {
            const int k0 = ks * 32 + q * 8;
            lr[ks][0] = *(const f32x4*)(lrg + k0);
            lr[ks][1] = *(const f32x4*)(lrg + k0 + 4);
        }
    }

    for (int it = 0; it < ITEMS_PER_WAVE; ++it) {
        // b2 folded into acc init
        f32x4 acc[4];
#pragma unroll
        for (int nt = 0; nt < 4; ++nt) {
            const float bb = b2f[nt];
            acc[nt] = (f32x4){bb, bb, bb, bb};
        }

#pragma unroll
        for (int ks = 0; ks < 4; ++ks) {           // K = 128 = 4 x 32
            float hv[8];
#pragma unroll
            for (int j = 0; j < 4; ++j) {
                hv[j]     = fast_silu(pk[ks][0][j] + lr[ks][0][j]);
                hv[4 + j] = fast_silu(pk[ks][1][j] + lr[ks][1][j]);
            }
            bf16x8 af = pack8_rhu(hv);
#pragma unroll
            for (int nt = 0; nt < 4; ++nt)         // 4 independent MFMA chains
                acc[nt] = __builtin_amdgcn_mfma_f32_16x16x32_bf16(af, wfr[nt * 4 + ks], acc[nt], 0, 0, 0);
        }

        // decode next item; prefetch ligand (always) and pocket (on jt/b
        // change) into the now-dead reg buffers, hidden under the epilogue.
        int bn = b, jtn = jt, atn = at;
        if (it != ITEMS_PER_WAVE - 1) {
            const int idn = id + 1;
            bn = idn / 320;
            const int rn = idn - bn * 320;
            jtn = rn >> 5;
            atn = rn & 31;
            const float* lrn = Z + (size_t)(bn * NLB + atn) * H1DIM;
#pragma unroll
            for (int ks = 0; ks < 4; ++ks) {
                const int k0 = ks * 32 + q * 8;
                lr[ks][0] = *(const f32x4*)(lrn + k0);
                lr[ks][1] = *(const f32x4*)(lrn + k0 + 4);
            }
            if (jtn != jt || bn != b) {            // wave-uniform branch
                const float* pkn = Z + (size_t)(NL_TOT + bn * NPB + jtn * JT_CHUNK + c) * H1DIM;
#pragma unroll
                for (int ks = 0; ks < 4; ++ks) {
                    const int k0 = ks * 32 + q * 8;
                    pk[ks][0] = *(const f32x4*)(pkn + k0);
                    pk[ks][1] = *(const f32x4*)(pkn + k0 + 4);
                }
            }
        }

        // epilogue (b2 already in acc): lane holds D[m=q*4+r][n=nt*16+c]
        {
            float s0 = 0.f, s1 = 0.f, s2 = 0.f, s3 = 0.f;
#pragma unroll
            for (int nt = 0; nt < 4; ++nt) {
                s0 += fast_silu(acc[nt][0]) * w3f[nt];
                s1 += fast_silu(acc[nt][1]) * w3f[nt];
                s2 += fast_silu(acc[nt][2]) * w3f[nt];
                s3 += fast_silu(acc[nt][3]) * w3f[nt];
            }
            s0 = rowsum16(s0);
            s1 = rowsum16(s1);
            s2 = rowsum16(s2);
            s3 = rowsum16(s3);
            if (c < 4) {
                float v = (c == 0) ? s0 : (c == 1) ? s1 : (c == 2) ? s2 : s3;
                const int e0 = (b * NLB + at) * NPB + jt * JT_CHUNK;
                out[e0 + q * 4 + c] = fmaxf(v + b3v, 0.0f);
            }
        }

        id += 1; b = bn; jt = jtn; at = atn;
    }
}

// ---------------------------------------------------------------------------
extern "C" void kernel_launch(void* const* d_in, const int* in_sizes, int n_in,
                              void* d_out, int out_size, void* d_ws, size_t ws_size,
                              hipStream_t stream)
{
    const float* s_lig = (const float*)d_in[0];
    const float* s_poc = (const float*)d_in[1];
    const float* W1    = (const float*)d_in[4];
    const float* b1    = (const float*)d_in[5];
    const float* W2    = (const float*)d_in[6];
    const float* b2    = (const float*)d_in[7];
    const float* W3    = (const float*)d_in[8];
    const float* b3    = (const float*)d_in[9];

    float* Z = (float*)d_ws;   // NROWS*H1DIM*4 = 12.58 MB workspace

    hipLaunchKernelGGL(proj_kernel, dim3(NROWS / 16 / 4 * 2), dim3(256), 0, stream,
                       s_lig, s_poc, W1, b1, Z);
    hipLaunchKernelGGL(edge_kernel, dim3(EDGE_BLOCKS), dim3(256), 0, stream,
                       Z, W2, b2, W3, b3, (float*)d_out);
}

// Round 5
// 139.724 us; speedup vs baseline: 1.0662x; 1.0662x over previous
//
#include <hip/hip_runtime.h>
#include <hip/hip_bf16.h>

// ---------------------------------------------------------------------------
// HiddenEdgeDistanceMLP on MI355X (gfx950)
//
// reference:  s = s_lig[l] + s_poc[p]          [E,256]
//             h1 = silu(s @ W1.T + b1)         [E,128]
//             h2 = silu(h1 @ W2.T + b2)        [E,64]
//             out = relu(h2 @ W3.T + b3)       [E]
//
// v17 (R4): BISECT of v16's failure. v16 changed two things vs the passing
//   v14: (a) block=(b,jt) barrier-free schedule, (b) packed <2 x float>
//   silu (v_pk_* path). It failed absmax 0.29. The schedule re-derives
//   clean (bijection onto the edge set, operand mapping identical to v14);
//   the pk-f32 path (neg-modifier folding into pk ops feeding v_exp) is the
//   prime suspect. v17 = (a) only: v14's VERBATIM scalar inner body + the
//   (b,jt) schedule. This also carries R1-R3's real lever: edge ran at
//   ~2 blocks/CU with ~35% latency bubbles; grid 1280 = exactly 5
//   blocks/CU (LDS 24.8KB fits 6, VGPR ~96 fits 5 waves/SIMD) -> resident
//   waves/SIMD ~2->5 cover the bubbles; 1280 stagings (vs 2560); zero
//   barriers after the initial one.
//   Math bitwise identical to v14/v12 -> absmax expected 0.001953125.
// v12/v14 mechanisms kept: 2-atoms-per-K-pass (shared W2-frag + pocket
//   reads), b2 folded into acc init, single rhu-bf16 h1 + 1 MFMA/nt, W2
//   B-frags fragment-ordered in LDS, DPP rowsum, perm packing, ligand
//   prefetch into dead regs, no min-waves bound (R3: VGPR cliff -> spills).
// ---------------------------------------------------------------------------

#define B_CPLX   128
#define NLB      32
#define NPB      160
#define SDIM     256
#define H1DIM    128
#define NL_TOT   (B_CPLX * NLB)         // 4096
#define NP_TOT   (B_CPLX * NPB)         // 20480
#define NROWS    (NL_TOT + NP_TOT)      // 24576
#define E_TOT    (B_CPLX * NLB * NPB)   // 655360

#define W1_LDS_STRIDE 264               // 256 + 8 bf16 pad
#define JT_CHUNK 16                     // pocket rows per block
#define ZP_STRIDE 132                   // 128 + 4 f32 pad

#define EDGE_BLOCKS (B_CPLX * 10)       // 1280 = (b, jt); 5 blocks/CU exact

typedef __bf16 bf16x8 __attribute__((ext_vector_type(8)));
typedef unsigned short ushortx8 __attribute__((ext_vector_type(8)));
typedef unsigned short ushortx4 __attribute__((ext_vector_type(4)));
typedef unsigned uintx4 __attribute__((ext_vector_type(4)));
typedef float f32x4 __attribute__((ext_vector_type(4)));

__device__ __forceinline__ unsigned short f2bf(float f) {
    unsigned u = __builtin_bit_cast(unsigned, f);
    u += 0x7FFFu + ((u >> 16) & 1u);          // round-to-nearest-even
    return (unsigned short)(u >> 16);
}

// v_perm_b32: pack hi16(x0) low, hi16(x1) high (1 op)
__device__ __forceinline__ unsigned perm_hi16u(unsigned u0, unsigned u1) {
    return __builtin_amdgcn_perm(u1, u0, 0x07060302u);
}

// round-half-up bf16 pair pack: bitpattern + 0x8000 then take hi16.
__device__ __forceinline__ unsigned pack2_rhu(float x0, float x1) {
    unsigned u0 = __builtin_bit_cast(unsigned, x0) + 0x8000u;
    unsigned u1 = __builtin_bit_cast(unsigned, x1) + 0x8000u;
    return perm_hi16u(u0, u1);
}

__device__ __forceinline__ bf16x8 pack8_rhu(const float* x) {
    uintx4 h;
#pragma unroll
    for (int j = 0; j < 4; ++j) h[j] = pack2_rhu(x[2 * j], x[2 * j + 1]);
    return __builtin_bit_cast(bf16x8, h);
}

// hi/lo exact split (proj only): hi = trunc bf16, lo = bf16(x - hi)
__device__ __forceinline__ void pack_split(const float* x, bf16x8& hi, bf16x8& lo) {
    uintx4 h, l;
#pragma unroll
    for (int j = 0; j < 4; ++j) {
        float x0 = x[2 * j], x1 = x[2 * j + 1];
        unsigned u0 = __builtin_bit_cast(unsigned, x0);
        unsigned u1 = __builtin_bit_cast(unsigned, x1);
        h[j] = perm_hi16u(u0, u1);
        float hf0 = __builtin_bit_cast(float, u0 & 0xFFFF0000u);
        float hf1 = __builtin_bit_cast(float, u1 & 0xFFFF0000u);
        l[j] = pack2_rhu(x0 - hf0, x1 - hf1);
    }
    hi = __builtin_bit_cast(bf16x8, h);
    lo = __builtin_bit_cast(bf16x8, l);
}

__device__ __forceinline__ float fast_silu(float x) {
    return x * __builtin_amdgcn_rcpf(1.0f + __expf(-x));
}

// full-rate 16-lane row reduction: v_add_f32 + dpp row_ror 1,2,4,8
__device__ __forceinline__ float rowsum16(float s) {
    int b;
    b = __builtin_bit_cast(int, s);
    b = __builtin_amdgcn_update_dpp(b, b, 0x121, 0xF, 0xF, false);  // ror:1
    s += __builtin_bit_cast(float, b);
    b = __builtin_bit_cast(int, s);
    b = __builtin_amdgcn_update_dpp(b, b, 0x122, 0xF, 0xF, false);  // ror:2
    s += __builtin_bit_cast(float, b);
    b = __builtin_bit_cast(int, s);
    b = __builtin_amdgcn_update_dpp(b, b, 0x124, 0xF, 0xF, false);  // ror:4
    s += __builtin_bit_cast(float, b);
    b = __builtin_bit_cast(int, s);
    b = __builtin_amdgcn_update_dpp(b, b, 0x128, 0xF, 0xF, false);  // ror:8
    s += __builtin_bit_cast(float, b);
    return s;
}

// ---------------------------------------------------------------------------
// Kernel 1: Z[m][n] = X[m] @ W1[n] (+ b1[n] if m is a ligand row)
//   768 blocks = 384 row-tile groups x 2 N-halves; hi/lo split -> Z ~exact.
//   (verbatim v12)
// ---------------------------------------------------------------------------
__global__ __launch_bounds__(256) void proj_kernel(
    const float* __restrict__ s_lig, const float* __restrict__ s_poc,
    const float* __restrict__ W1,    const float* __restrict__ b1,
    float* __restrict__ Z)
{
    __shared__ unsigned short w1s[64 * W1_LDS_STRIDE];   // 33.8 KB

    const int tid  = threadIdx.x;
    const int tg   = blockIdx.x >> 1;             // row-tile group 0..383
    const int half = blockIdx.x & 1;              // N half

    {
        const f32x4* w4 = (const f32x4*)(W1 + (size_t)half * 64 * SDIM);  // 4096 units
#pragma unroll
        for (int r = 0; r < 2; ++r) {
            f32x4 t[8];
#pragma unroll
            for (int s = 0; s < 8; ++s) t[s] = w4[tid + (r * 8 + s) * 256];
#pragma unroll
            for (int s = 0; s < 8; ++s) {
                const int u = tid + (r * 8 + s) * 256;
                const int n = u >> 6;             // 64 f32x4 per 256-col row
                const int k4 = u & 63;
                ushortx4 us;
#pragma unroll
                for (int j = 0; j < 4; ++j) us[j] = f2bf(t[s][j]);
                *(ushortx4*)(&w1s[n * W1_LDS_STRIDE + k4 * 4]) = us;
            }
        }
    }
    __syncthreads();

    const int lane = tid & 63;
    const int widx = tid >> 6;
    const int c    = lane & 15;
    const int q    = lane >> 4;
    const int tile = tg * 4 + widx;               // 0..1535
    const int row  = tile * 16 + c;

    const float* src = (row < NL_TOT) ? (s_lig + (size_t)row * SDIM)
                                      : (s_poc + (size_t)(row - NL_TOT) * SDIM);

    f32x4 acc[4];
#pragma unroll
    for (int nt = 0; nt < 4; ++nt) acc[nt] = (f32x4){0.f, 0.f, 0.f, 0.f};

#pragma unroll
    for (int ks = 0; ks < 8; ++ks) {              // K = 256 = 8 x 32
        const int k0 = ks * 32 + q * 8;
        f32x4 xa = *reinterpret_cast<const f32x4*>(src + k0);
        f32x4 xb = *reinterpret_cast<const f32x4*>(src + k0 + 4);
        float xv[8] = {xa[0], xa[1], xa[2], xa[3], xb[0], xb[1], xb[2], xb[3]};
        bf16x8 ahi, alo;
        pack_split(xv, ahi, alo);
        bf16x8 bfrag[4];
#pragma unroll
        for (int nt = 0; nt < 4; ++nt)
            bfrag[nt] = *reinterpret_cast<const bf16x8*>(
                &w1s[(nt * 16 + c) * W1_LDS_STRIDE + k0]);
#pragma unroll
        for (int nt = 0; nt < 4; ++nt)            // hi pass (dep distance 4)
            acc[nt] = __builtin_amdgcn_mfma_f32_16x16x32_bf16(ahi, bfrag[nt], acc[nt], 0, 0, 0);
#pragma unroll
        for (int nt = 0; nt < 4; ++nt)            // lo pass
            acc[nt] = __builtin_amdgcn_mfma_f32_16x16x32_bf16(alo, bfrag[nt], acc[nt], 0, 0, 0);
    }

    // C/D layout: col n' = lane&15, row m = q*4 + reg
    const int mb = tile * 16 + q * 4;
#pragma unroll
    for (int nt = 0; nt < 4; ++nt) {
        const int n = half * 64 + nt * 16 + c;
        const float bias = b1[n];
#pragma unroll
        for (int r = 0; r < 4; ++r) {
            const int m = mb + r;
            float v = acc[nt][r];
            if (m < NL_TOT) v += bias;            // fold b1 into ligand rows only
            Z[(size_t)m * H1DIM + n] = v;
        }
    }
}

// ---------------------------------------------------------------------------
// Kernel 2: block = (complex b, pocket chunk jt); 1280 blocks x 4 waves.
//   4 atom-group iterations (g = 0..3); wave handles pair (2 atoms) per g.
//   zp + W2 staged once; ZERO barriers after the initial one.
//   Inner body is VERBATIM v12/v14 scalar code.
// ---------------------------------------------------------------------------
__global__ __launch_bounds__(256) void edge_kernel(
    const float* __restrict__ Z,
    const float* __restrict__ W2, const float* __restrict__ b2,
    const float* __restrict__ W3, const float* __restrict__ b3,
    float* __restrict__ out)
{
    __shared__ float zp[JT_CHUNK * ZP_STRIDE];            // 8.4 KB
    __shared__ unsigned short w2s[16 * 64 * 8];           // 16 KB frag-ordered

    const int tid = threadIdx.x;
    const int b   = blockIdx.x / 10;
    const int jt  = blockIdx.x - b * 10;          // 0..9

    // stage W2 as bf16 B-fragments, fragment-ordered (once per block):
    //   slot = chunk*64 + lane, chunk = nt*4 + ks;
    //   frag(lane) = W2[n = nt*16 + (lane&15)][ks*32 + (lane>>4)*8 .. +8]
    {
#pragma unroll
        for (int s = 0; s < 4; ++s) {
            const int slot   = tid + s * 256;             // 0..1023
            const int lane_s = slot & 63;
            const int chunk  = slot >> 6;
            const int nt     = chunk >> 2;
            const int ks     = chunk & 3;
            const int n      = nt * 16 + (lane_s & 15);
            const int k0     = ks * 32 + (lane_s >> 4) * 8;
            const float* wsrc = W2 + (size_t)n * H1DIM + k0;
            f32x4 wa = *(const f32x4*)wsrc;
            f32x4 wb = *(const f32x4*)(wsrc + 4);
            float wv[8] = {wa[0], wa[1], wa[2], wa[3], wb[0], wb[1], wb[2], wb[3]};
            ushortx8 us;
#pragma unroll
            for (int j = 0; j < 8; ++j) us[j] = f2bf(wv[j]);   // RNE for weights
            *(ushortx8*)(&w2s[slot * 8]) = us;
        }
    }

    // stage pocket rows: 16 rows x 128 f32 = 512 f32x4, 2 per thread
    {
        const float* zpg = Z + (size_t)(NL_TOT + b * NPB + jt * JT_CHUNK) * H1DIM;
#pragma unroll
        for (int s = 0; s < 2; ++s) {
            const int u   = tid + s * 256;
            const int row = u >> 5;
            const int c4  = u & 31;
            f32x4 v = *(const f32x4*)(zpg + (size_t)row * H1DIM + c4 * 4);
            *(f32x4*)(&zp[row * ZP_STRIDE + c4 * 4]) = v;
        }
    }

    const int lane = tid & 63;
    const int widx = tid >> 6;
    const int c    = lane & 15;
    const int q    = lane >> 4;

    float b2f[4], w3f[4];
#pragma unroll
    for (int nt = 0; nt < 4; ++nt) {
        b2f[nt] = b2[nt * 16 + c];
        w3f[nt] = W3[nt * 16 + c];
    }
    const float b3v = b3[0];

    const float* lgbase = Z + (size_t)(b * NLB) * H1DIM;   // ligand rows of b

    // ligand pair rows for g=0 (wave widx: atoms widx*2, widx*2+1)
    f32x4 lgA[4][2], lgB[4][2];
    {
        const float* lr0 = lgbase + (size_t)(widx * 2) * H1DIM;
#pragma unroll
        for (int ks = 0; ks < 4; ++ks) {
            const int k0 = ks * 32 + q * 8;
            lgA[ks][0] = *(const f32x4*)(lr0 + k0);
            lgA[ks][1] = *(const f32x4*)(lr0 + k0 + 4);
            lgB[ks][0] = *(const f32x4*)(lr0 + H1DIM + k0);
            lgB[ks][1] = *(const f32x4*)(lr0 + H1DIM + k0 + 4);
        }
    }

    __syncthreads();   // W2 + zp visible; the ONLY barrier

    const float* prow = &zp[c * ZP_STRIDE];
    const unsigned short* wbase = &w2s[lane * 8];          // + chunk*512 ushorts

#pragma unroll
    for (int g = 0; g < 4; ++g) {                  // atom groups of 8
        // b2 folded into acc init (saves epilogue adds)
        f32x4 acc0[4], acc1[4];
#pragma unroll
        for (int nt = 0; nt < 4; ++nt) {
            const float bb = b2f[nt];
            acc0[nt] = (f32x4){bb, bb, bb, bb};
            acc1[nt] = (f32x4){bb, bb, bb, bb};
        }

#pragma unroll
        for (int ks = 0; ks < 4; ++ks) {           // K = 128 = 4 x 32
            const int k0 = ks * 32 + q * 8;
            bf16x8 bfr[4];
#pragma unroll
            for (int nt = 0; nt < 4; ++nt)         // conflict-free ds_read_b128
                bfr[nt] = *(const bf16x8*)(wbase + (nt * 4 + ks) * 512);
            f32x4 pa = *(const f32x4*)(prow + k0);
            f32x4 pb = *(const f32x4*)(prow + k0 + 4);
            float hv0[8], hv1[8];
#pragma unroll
            for (int j = 0; j < 4; ++j) {
                hv0[j]     = fast_silu(pa[j] + lgA[ks][0][j]);
                hv0[4 + j] = fast_silu(pb[j] + lgA[ks][1][j]);
                hv1[j]     = fast_silu(pa[j] + lgB[ks][0][j]);
                hv1[4 + j] = fast_silu(pb[j] + lgB[ks][1][j]);
            }
            bf16x8 a0f = pack8_rhu(hv0);
            bf16x8 a1f = pack8_rhu(hv1);
#pragma unroll
            for (int nt = 0; nt < 4; ++nt)         // 8 independent MFMAs
                acc0[nt] = __builtin_amdgcn_mfma_f32_16x16x32_bf16(a0f, bfr[nt], acc0[nt], 0, 0, 0);
#pragma unroll
            for (int nt = 0; nt < 4; ++nt)
                acc1[nt] = __builtin_amdgcn_mfma_f32_16x16x32_bf16(a1f, bfr[nt], acc1[nt], 0, 0, 0);
        }

        // prefetch next group's ligand pair into the now-dead lg buffers
        // (latency hidden under the epilogue); rows b*32 + (g+1)*8 + ...
        if (g != 3) {
            const float* lrn = lgbase + (size_t)((g + 1) * 8 + widx * 2) * H1DIM;
#pragma unroll
            for (int ks = 0; ks < 4; ++ks) {
                const int k0 = ks * 32 + q * 8;
                lgA[ks][0] = *(const f32x4*)(lrn + k0);
                lgA[ks][1] = *(const f32x4*)(lrn + k0 + 4);
                lgB[ks][0] = *(const f32x4*)(lrn + H1DIM + k0);
                lgB[ks][1] = *(const f32x4*)(lrn + H1DIM + k0 + 4);
            }
        }

        // epilogues (b2 already in acc): lane holds D[m=q*4+r][n=nt*16+c]
#pragma unroll
        for (int at = 0; at < 2; ++at) {
            const f32x4* A = at ? acc1 : acc0;
            float s0 = 0.f, s1 = 0.f, s2 = 0.f, s3 = 0.f;
#pragma unroll
            for (int nt = 0; nt < 4; ++nt) {
                s0 += fast_silu(A[nt][0]) * w3f[nt];
                s1 += fast_silu(A[nt][1]) * w3f[nt];
                s2 += fast_silu(A[nt][2]) * w3f[nt];
                s3 += fast_silu(A[nt][3]) * w3f[nt];
            }
            s0 = rowsum16(s0);
            s1 = rowsum16(s1);
            s2 = rowsum16(s2);
            s3 = rowsum16(s3);
            if (c < 4) {
                float v = (c == 0) ? s0 : (c == 1) ? s1 : (c == 2) ? s2 : s3;
                const int e0 = (b * NLB + g * 8 + widx * 2 + at) * NPB + jt * JT_CHUNK;
                out[e0 + q * 4 + c] = fmaxf(v + b3v, 0.0f);
            }
        }
    }
}

// ---------------------------------------------------------------------------
extern "C" void kernel_launch(void* const* d_in, const int* in_sizes, int n_in,
                              void* d_out, int out_size, void* d_ws, size_t ws_size,
                              hipStream_t stream)
{
    const float* s_lig = (const float*)d_in[0];
    const float* s_poc = (const float*)d_in[1];
    const float* W1    = (const float*)d_in[4];
    const float* b1    = (const float*)d_in[5];
    const float* W2    = (const float*)d_in[6];
    const float* b2    = (const float*)d_in[7];
    const float* W3    = (const float*)d_in[8];
    const float* b3    = (const float*)d_in[9];

    float* Z = (float*)d_ws;   // NROWS*H1DIM*4 = 12.58 MB workspace

    hipLaunchKernelGGL(proj_kernel, dim3(NROWS / 16 / 4 * 2), dim3(256), 0, stream,
                       s_lig, s_poc, W1, b1, Z);
    hipLaunchKernelGGL(edge_kernel, dim3(EDGE_BLOCKS), dim3(256), 0, stream,
                       Z, W2, b2, W3, b3, (float*)d_out);
}

// Round 6
// 138.695 us; speedup vs baseline: 1.0741x; 1.0074x over previous
//
#include <hip/hip_runtime.h>
#include <hip/hip_bf16.h>

// ---------------------------------------------------------------------------
// HiddenEdgeDistanceMLP on MI355X (gfx950)
//
// reference:  s = s_lig[l] + s_poc[p]          [E,256]
//             h1 = silu(s @ W1.T + b1)         [E,128]
//             h2 = silu(h1 @ W2.T + b2)        [E,64]
//             out = relu(h2 @ W3.T + b3)       [E]
//
// v18 (R5): LIGAND ROWS -> LDS; kill the unified-register-file occupancy cap.
//   Model (fits R0-R4): per 2-atom item the SIMD issues ~4160cy (trans 1536 +
//   VALU ~2600) vs 6120cy wall = 32% idle; OccupancyPercent ~18-25% was RIGHT:
//   gfx950's UNIFIED VGPR/AGPR file means live state (lgA/lgB 64 + acc 32 +
//   temps, > VGPR_Count 88) gets parked in AGPRs -> total ~180-250 regs/wave
//   -> ~1.4-2 waves/SIMD -> per-wave latency (trans chains, lgkm) exposed.
//   Every R0-R4 schedule variant kept the same footprint -> invariant 51us.
//   Fix: move the 64-reg ligand buffers to a 16KB LDS tile zl[32][128]
//   (all ligand rows of complex b, staged once, shared by 4 waves x 4 g's;
//   reads are 16-lane-broadcast, conflict-free, stride 128 exact). Prefetch
//   machinery deleted. Live state -> acc+transients (~<=128 unified) ->
//   LDS caps residency at 3 blocks/CU = 3 waves/SIMD (~2x current).
//   Math BITWISE identical to v17 (same f32 zl bits via LDS, same silu/RHU
//   pack/MFMA chain order) -> absmax expected exactly 0.001953125.
// v17 mechanisms kept: block=(b,jt) grid 1280, zero barriers after the
//   initial one, 2-atoms-per-K-pass, b2 folded into acc init, single
//   rhu-bf16 h1 + 1 MFMA/nt, W2 B-frags fragment-ordered in LDS, DPP
//   rowsum, perm packing, no min-waves bound (VGPR cliff -> spills).
// ---------------------------------------------------------------------------

#define B_CPLX   128
#define NLB      32
#define NPB      160
#define SDIM     256
#define H1DIM    128
#define NL_TOT   (B_CPLX * NLB)         // 4096
#define NP_TOT   (B_CPLX * NPB)         // 20480
#define NROWS    (NL_TOT + NP_TOT)      // 24576
#define E_TOT    (B_CPLX * NLB * NPB)   // 655360

#define W1_LDS_STRIDE 264               // 256 + 8 bf16 pad
#define JT_CHUNK 16                     // pocket rows per block
#define ZP_STRIDE 132                   // 128 + 4 f32 pad (2-way banks, free)

#define EDGE_BLOCKS (B_CPLX * 10)       // 1280 = (b, jt)

typedef __bf16 bf16x8 __attribute__((ext_vector_type(8)));
typedef unsigned short ushortx8 __attribute__((ext_vector_type(8)));
typedef unsigned short ushortx4 __attribute__((ext_vector_type(4)));
typedef unsigned uintx4 __attribute__((ext_vector_type(4)));
typedef float f32x4 __attribute__((ext_vector_type(4)));

__device__ __forceinline__ unsigned short f2bf(float f) {
    unsigned u = __builtin_bit_cast(unsigned, f);
    u += 0x7FFFu + ((u >> 16) & 1u);          // round-to-nearest-even
    return (unsigned short)(u >> 16);
}

// v_perm_b32: pack hi16(x0) low, hi16(x1) high (1 op)
__device__ __forceinline__ unsigned perm_hi16u(unsigned u0, unsigned u1) {
    return __builtin_amdgcn_perm(u1, u0, 0x07060302u);
}

// round-half-up bf16 pair pack: bitpattern + 0x8000 then take hi16.
__device__ __forceinline__ unsigned pack2_rhu(float x0, float x1) {
    unsigned u0 = __builtin_bit_cast(unsigned, x0) + 0x8000u;
    unsigned u1 = __builtin_bit_cast(unsigned, x1) + 0x8000u;
    return perm_hi16u(u0, u1);
}

__device__ __forceinline__ bf16x8 pack8_rhu(const float* x) {
    uintx4 h;
#pragma unroll
    for (int j = 0; j < 4; ++j) h[j] = pack2_rhu(x[2 * j], x[2 * j + 1]);
    return __builtin_bit_cast(bf16x8, h);
}

// hi/lo exact split (proj only): hi = trunc bf16, lo = bf16(x - hi)
__device__ __forceinline__ void pack_split(const float* x, bf16x8& hi, bf16x8& lo) {
    uintx4 h, l;
#pragma unroll
    for (int j = 0; j < 4; ++j) {
        float x0 = x[2 * j], x1 = x[2 * j + 1];
        unsigned u0 = __builtin_bit_cast(unsigned, x0);
        unsigned u1 = __builtin_bit_cast(unsigned, x1);
        h[j] = perm_hi16u(u0, u1);
        float hf0 = __builtin_bit_cast(float, u0 & 0xFFFF0000u);
        float hf1 = __builtin_bit_cast(float, u1 & 0xFFFF0000u);
        l[j] = pack2_rhu(x0 - hf0, x1 - hf1);
    }
    hi = __builtin_bit_cast(bf16x8, h);
    lo = __builtin_bit_cast(bf16x8, l);
}

__device__ __forceinline__ float fast_silu(float x) {
    return x * __builtin_amdgcn_rcpf(1.0f + __expf(-x));
}

// full-rate 16-lane row reduction: v_add_f32 + dpp row_ror 1,2,4,8
__device__ __forceinline__ float rowsum16(float s) {
    int b;
    b = __builtin_bit_cast(int, s);
    b = __builtin_amdgcn_update_dpp(b, b, 0x121, 0xF, 0xF, false);  // ror:1
    s += __builtin_bit_cast(float, b);
    b = __builtin_bit_cast(int, s);
    b = __builtin_amdgcn_update_dpp(b, b, 0x122, 0xF, 0xF, false);  // ror:2
    s += __builtin_bit_cast(float, b);
    b = __builtin_bit_cast(int, s);
    b = __builtin_amdgcn_update_dpp(b, b, 0x124, 0xF, 0xF, false);  // ror:4
    s += __builtin_bit_cast(float, b);
    b = __builtin_bit_cast(int, s);
    b = __builtin_amdgcn_update_dpp(b, b, 0x128, 0xF, 0xF, false);  // ror:8
    s += __builtin_bit_cast(float, b);
    return s;
}

// ---------------------------------------------------------------------------
// Kernel 1: Z[m][n] = X[m] @ W1[n] (+ b1[n] if m is a ligand row)
//   768 blocks = 384 row-tile groups x 2 N-halves; hi/lo split -> Z ~exact.
//   (verbatim v12)
// ---------------------------------------------------------------------------
__global__ __launch_bounds__(256) void proj_kernel(
    const float* __restrict__ s_lig, const float* __restrict__ s_poc,
    const float* __restrict__ W1,    const float* __restrict__ b1,
    float* __restrict__ Z)
{
    __shared__ unsigned short w1s[64 * W1_LDS_STRIDE];   // 33.8 KB

    const int tid  = threadIdx.x;
    const int tg   = blockIdx.x >> 1;             // row-tile group 0..383
    const int half = blockIdx.x & 1;              // N half

    {
        const f32x4* w4 = (const f32x4*)(W1 + (size_t)half * 64 * SDIM);  // 4096 units
#pragma unroll
        for (int r = 0; r < 2; ++r) {
            f32x4 t[8];
#pragma unroll
            for (int s = 0; s < 8; ++s) t[s] = w4[tid + (r * 8 + s) * 256];
#pragma unroll
            for (int s = 0; s < 8; ++s) {
                const int u = tid + (r * 8 + s) * 256;
                const int n = u >> 6;             // 64 f32x4 per 256-col row
                const int k4 = u & 63;
                ushortx4 us;
#pragma unroll
                for (int j = 0; j < 4; ++j) us[j] = f2bf(t[s][j]);
                *(ushortx4*)(&w1s[n * W1_LDS_STRIDE + k4 * 4]) = us;
            }
        }
    }
    __syncthreads();

    const int lane = tid & 63;
    const int widx = tid >> 6;
    const int c    = lane & 15;
    const int q    = lane >> 4;
    const int tile = tg * 4 + widx;               // 0..1535
    const int row  = tile * 16 + c;

    const float* src = (row < NL_TOT) ? (s_lig + (size_t)row * SDIM)
                                      : (s_poc + (size_t)(row - NL_TOT) * SDIM);

    f32x4 acc[4];
#pragma unroll
    for (int nt = 0; nt < 4; ++nt) acc[nt] = (f32x4){0.f, 0.f, 0.f, 0.f};

#pragma unroll
    for (int ks = 0; ks < 8; ++ks) {              // K = 256 = 8 x 32
        const int k0 = ks * 32 + q * 8;
        f32x4 xa = *reinterpret_cast<const f32x4*>(src + k0);
        f32x4 xb = *reinterpret_cast<const f32x4*>(src + k0 + 4);
        float xv[8] = {xa[0], xa[1], xa[2], xa[3], xb[0], xb[1], xb[2], xb[3]};
        bf16x8 ahi, alo;
        pack_split(xv, ahi, alo);
        bf16x8 bfrag[4];
#pragma unroll
        for (int nt = 0; nt < 4; ++nt)
            bfrag[nt] = *reinterpret_cast<const bf16x8*>(
                &w1s[(nt * 16 + c) * W1_LDS_STRIDE + k0]);
#pragma unroll
        for (int nt = 0; nt < 4; ++nt)            // hi pass (dep distance 4)
            acc[nt] = __builtin_amdgcn_mfma_f32_16x16x32_bf16(ahi, bfrag[nt], acc[nt], 0, 0, 0);
#pragma unroll
        for (int nt = 0; nt < 4; ++nt)            // lo pass
            acc[nt] = __builtin_amdgcn_mfma_f32_16x16x32_bf16(alo, bfrag[nt], acc[nt], 0, 0, 0);
    }

    // C/D layout: col n' = lane&15, row m = q*4 + reg
    const int mb = tile * 16 + q * 4;
#pragma unroll
    for (int nt = 0; nt < 4; ++nt) {
        const int n = half * 64 + nt * 16 + c;
        const float bias = b1[n];
#pragma unroll
        for (int r = 0; r < 4; ++r) {
            const int m = mb + r;
            float v = acc[nt][r];
            if (m < NL_TOT) v += bias;            // fold b1 into ligand rows only
            Z[(size_t)m * H1DIM + n] = v;
        }
    }
}

// ---------------------------------------------------------------------------
// Kernel 2: block = (complex b, pocket chunk jt); 1280 blocks x 4 waves.
//   All 32 ligand rows of b staged in LDS (zl), shared by 4 waves x 4 g's.
//   zp + zl + W2 staged once; ZERO barriers after the initial one.
//   Inner math is VERBATIM v17 (ligand operands now sourced from LDS).
// ---------------------------------------------------------------------------
__global__ __launch_bounds__(256) void edge_kernel(
    const float* __restrict__ Z,
    const float* __restrict__ W2, const float* __restrict__ b2,
    const float* __restrict__ W3, const float* __restrict__ b3,
    float* __restrict__ out)
{
    __shared__ float zp[JT_CHUNK * ZP_STRIDE];            // 8.4 KB
    __shared__ float zl[NLB * H1DIM];                     // 16 KB, stride 128
    __shared__ unsigned short w2s[16 * 64 * 8];           // 16 KB frag-ordered
    // total 40.25 KB -> 3 blocks/CU (LDS-capped), ~3 waves/SIMD

    const int tid = threadIdx.x;
    const int b   = blockIdx.x / 10;
    const int jt  = blockIdx.x - b * 10;          // 0..9

    // stage W2 as bf16 B-fragments, fragment-ordered (once per block):
    //   slot = chunk*64 + lane, chunk = nt*4 + ks;
    //   frag(lane) = W2[n = nt*16 + (lane&15)][ks*32 + (lane>>4)*8 .. +8]
    {
#pragma unroll
        for (int s = 0; s < 4; ++s) {
            const int slot   = tid + s * 256;             // 0..1023
            const int lane_s = slot & 63;
            const int chunk  = slot >> 6;
            const int nt     = chunk >> 2;
            const int ks     = chunk & 3;
            const int n      = nt * 16 + (lane_s & 15);
            const int k0     = ks * 32 + (lane_s >> 4) * 8;
            const float* wsrc = W2 + (size_t)n * H1DIM + k0;
            f32x4 wa = *(const f32x4*)wsrc;
            f32x4 wb = *(const f32x4*)(wsrc + 4);
            float wv[8] = {wa[0], wa[1], wa[2], wa[3], wb[0], wb[1], wb[2], wb[3]};
            ushortx8 us;
#pragma unroll
            for (int j = 0; j < 8; ++j) us[j] = f2bf(wv[j]);   // RNE for weights
            *(ushortx8*)(&w2s[slot * 8]) = us;
        }
    }

    // stage pocket rows: 16 rows x 128 f32 = 512 f32x4, 2 per thread
    {
        const float* zpg = Z + (size_t)(NL_TOT + b * NPB + jt * JT_CHUNK) * H1DIM;
#pragma unroll
        for (int s = 0; s < 2; ++s) {
            const int u   = tid + s * 256;
            const int row = u >> 5;
            const int c4  = u & 31;
            f32x4 v = *(const f32x4*)(zpg + (size_t)row * H1DIM + c4 * 4);
            *(f32x4*)(&zp[row * ZP_STRIDE + c4 * 4]) = v;
        }
    }

    // stage ALL 32 ligand rows of b: 32 x 128 f32 = 1024 f32x4, 4 per thread
    // (stride 128 exact: reads below are wave-uniform per 16-lane group ->
    //  LDS broadcast, conflict-free regardless of stride)
    {
        const float* zlg = Z + (size_t)(b * NLB) * H1DIM;
#pragma unroll
        for (int s = 0; s < 4; ++s) {
            const int u   = tid + s * 256;                // 0..1023
            const int row = u >> 5;
            const int c4  = u & 31;
            f32x4 v = *(const f32x4*)(zlg + (size_t)row * H1DIM + c4 * 4);
            *(f32x4*)(&zl[row * H1DIM + c4 * 4]) = v;
        }
    }

    const int lane = tid & 63;
    const int widx = tid >> 6;
    const int c    = lane & 15;
    const int q    = lane >> 4;

    float b2f[4], w3f[4];
#pragma unroll
    for (int nt = 0; nt < 4; ++nt) {
        b2f[nt] = b2[nt * 16 + c];
        w3f[nt] = W3[nt * 16 + c];
    }
    const float b3v = b3[0];

    __syncthreads();   // W2 + zp + zl visible; the ONLY barrier

    const float* prow = &zp[c * ZP_STRIDE];
    const unsigned short* wbase = &w2s[lane * 8];          // + chunk*512 ushorts

#pragma unroll
    for (int g = 0; g < 4; ++g) {                  // atom groups of 8
        // b2 folded into acc init (saves epilogue adds)
        f32x4 acc0[4], acc1[4];
#pragma unroll
        for (int nt = 0; nt < 4; ++nt) {
            const float bb = b2f[nt];
            acc0[nt] = (f32x4){bb, bb, bb, bb};
            acc1[nt] = (f32x4){bb, bb, bb, bb};
        }

        // wave's atom pair for this group: i0 = g*8 + widx*2, i0+1
        const float* lrow0 = &zl[(g * 8 + widx * 2) * H1DIM];

#pragma unroll
        for (int ks = 0; ks < 4; ++ks) {           // K = 128 = 4 x 32
            const int k0 = ks * 32 + q * 8;
            bf16x8 bfr[4];
#pragma unroll
            for (int nt = 0; nt < 4; ++nt)         // conflict-free ds_read_b128
                bfr[nt] = *(const bf16x8*)(wbase + (nt * 4 + ks) * 512);
            f32x4 pa = *(const f32x4*)(prow + k0);
            f32x4 pb = *(const f32x4*)(prow + k0 + 4);
            // ligand operands from LDS (16-lane broadcast reads)
            f32x4 la0 = *(const f32x4*)(lrow0 + k0);
            f32x4 la1 = *(const f32x4*)(lrow0 + k0 + 4);
            f32x4 lb0 = *(const f32x4*)(lrow0 + H1DIM + k0);
            f32x4 lb1 = *(const f32x4*)(lrow0 + H1DIM + k0 + 4);
            float hv0[8], hv1[8];
#pragma unroll
            for (int j = 0; j < 4; ++j) {
                hv0[j]     = fast_silu(pa[j] + la0[j]);
                hv0[4 + j] = fast_silu(pb[j] + la1[j]);
                hv1[j]     = fast_silu(pa[j] + lb0[j]);
                hv1[4 + j] = fast_silu(pb[j] + lb1[j]);
            }
            bf16x8 a0f = pack8_rhu(hv0);
            bf16x8 a1f = pack8_rhu(hv1);
#pragma unroll
            for (int nt = 0; nt < 4; ++nt)         // 8 independent MFMAs
                acc0[nt] = __builtin_amdgcn_mfma_f32_16x16x32_bf16(a0f, bfr[nt], acc0[nt], 0, 0, 0);
#pragma unroll
            for (int nt = 0; nt < 4; ++nt)
                acc1[nt] = __builtin_amdgcn_mfma_f32_16x16x32_bf16(a1f, bfr[nt], acc1[nt], 0, 0, 0);
        }

        // epilogues (b2 already in acc): lane holds D[m=q*4+r][n=nt*16+c]
#pragma unroll
        for (int at = 0; at < 2; ++at) {
            const f32x4* A = at ? acc1 : acc0;
            float s0 = 0.f, s1 = 0.f, s2 = 0.f, s3 = 0.f;
#pragma unroll
            for (int nt = 0; nt < 4; ++nt) {
                s0 += fast_silu(A[nt][0]) * w3f[nt];
                s1 += fast_silu(A[nt][1]) * w3f[nt];
                s2 += fast_silu(A[nt][2]) * w3f[nt];
                s3 += fast_silu(A[nt][3]) * w3f[nt];
            }
            s0 = rowsum16(s0);
            s1 = rowsum16(s1);
            s2 = rowsum16(s2);
            s3 = rowsum16(s3);
            if (c < 4) {
                float v = (c == 0) ? s0 : (c == 1) ? s1 : (c == 2) ? s2 : s3;
                const int e0 = (b * NLB + g * 8 + widx * 2 + at) * NPB + jt * JT_CHUNK;
                out[e0 + q * 4 + c] = fmaxf(v + b3v, 0.0f);
            }
        }
    }
}

// ---------------------------------------------------------------------------
extern "C" void kernel_launch(void* const* d_in, const int* in_sizes, int n_in,
                              void* d_out, int out_size, void* d_ws, size_t ws_size,
                              hipStream_t stream)
{
    const float* s_lig = (const float*)d_in[0];
    const float* s_poc = (const float*)d_in[1];
    const float* W1    = (const float*)d_in[4];
    const float* b1    = (const float*)d_in[5];
    const float* W2    = (const float*)d_in[6];
    const float* b2    = (const float*)d_in[7];
    const float* W3    = (const float*)d_in[8];
    const float* b3    = (const float*)d_in[9];

    float* Z = (float*)d_ws;   // NROWS*H1DIM*4 = 12.58 MB workspace

    hipLaunchKernelGGL(proj_kernel, dim3(NROWS / 16 / 4 * 2), dim3(256), 0, stream,
                       s_lig, s_poc, W1, b1, Z);
    hipLaunchKernelGGL(edge_kernel, dim3(EDGE_BLOCKS), dim3(256), 0, stream,
                       Z, W2, b2, W3, b3, (float*)d_out);
}